// Round 20
// baseline (67.545 us; speedup 1.0000x reference)
//
#include <hip/hip_runtime.h>
#include <math.h>

// Problem constants (ConvAttention: B=8, C=192, H=W=28, heads=6, ch=32, G=4)
namespace {
constexpr int kB = 8;
constexpr int kC = 192;
constexpr int kH = 28;
constexpr int kW = 28;
constexpr int kN = 784;          // kH * kW
constexpr int kHEADS = 6;
constexpr int kG = 4;
constexpr float kEPS = 1e-5f;
// 192^-0.5 * log2(e): scores in log2-units so softmax uses native 2^x.
// FIXED shift m=0 (shift-invariant; scores are O(0.3) in log2 units).
constexpr float kQS = 0.07216878364870322f * 1.4426950408889634f;
constexpr int kNP = 800;         // padded key-row stride (25 tiles of 32)
}

typedef __attribute__((ext_vector_type(8))) short bf16x8;
typedef __attribute__((ext_vector_type(4))) float f32x4;

union VU { ushort4 hlf[2]; bf16x8 v; };

// f32 -> bf16 bits, round-to-nearest-even
static __device__ __forceinline__ unsigned short f2bf(float f) {
    union { float f; unsigned int u; } v; v.f = f;
    unsigned int r = v.u + 0x7fffu + ((v.u >> 16) & 1u);
    return (unsigned short)(r >> 16);
}

static __device__ __forceinline__ float fexp2(float x) {
    return __builtin_amdgcn_exp2f(x);   // native v_exp_f32 (2^x)
}

// ---------------------------------------------------------------------------
// K0: prep. Wq/Wk/Wv f32->bf16; Wo bf16 with column perm
// Wo'[o][h*32+c] = po_w[o][c*6+h]; dwT[br][tap][c] = dw_br[c*9+tap] (f32).
// 165 blocks x 256 threads = 42240 >= 36864 (W) + 5184 (dwT).
// ---------------------------------------------------------------------------
__global__ __launch_bounds__(256) void prep_kernel(
    const float* __restrict__ pqw, const float* __restrict__ pkw,
    const float* __restrict__ pvw, const float* __restrict__ pow_,
    const float* __restrict__ dwq, const float* __restrict__ dwk,
    const float* __restrict__ dwv,
    unsigned short* __restrict__ Wq, unsigned short* __restrict__ Wk,
    unsigned short* __restrict__ Wv, unsigned short* __restrict__ Wo,
    float* __restrict__ dwT)
{
    const int aux = blockIdx.x * 256 + threadIdx.x;
    if (aux < 36864) {
        const int e0 = aux * 4;
        const int mat = e0 / (kC * kC);
        const int r = e0 % (kC * kC);
        if (mat < 3) {
            const float* src = (mat == 0) ? pqw : (mat == 1) ? pkw : pvw;
            unsigned short* dst = (mat == 0) ? Wq : (mat == 1) ? Wk : Wv;
            const f32x4 v = *(const f32x4*)&src[r];
            ushort4 p;
            p.x = f2bf(v[0]); p.y = f2bf(v[1]); p.z = f2bf(v[2]); p.w = f2bf(v[3]);
            *(ushort4*)&dst[r] = p;
        } else {
            const int o = r / kC, c0 = r % kC;
            ushort4 p;
            unsigned short* pp = &p.x;
#pragma unroll
            for (int e = 0; e < 4; ++e) {
                const int c = c0 + e;
                pp[e] = f2bf(pow_[o * kC + (c & 31) * kHEADS + (c >> 5)]);
            }
            *(ushort4*)&Wo[o * kC + c0] = p;
        }
    } else {
        const int r = aux - 36864;           // 0..5375; valid < 5184
        if (r < 3 * 9 * kC) {
            const int br = r / (9 * kC);
            const int rem = r % (9 * kC);
            const int tap = rem / kC, c = rem % kC;
            const float* dw = (br == 0) ? dwq : (br == 1) ? dwk : dwv;
            dwT[r] = dw[c * 9 + tap];
        }
    }
}

// ---------------------------------------------------------------------------
// K1: FUSED dw3x3+BN + 1x1 projection — vectorized Phase A + W-prefetch +
// XCD-aware block mapping (b = bid & 7). 392 blocks x 768 threads.
// (unchanged from round 19)
// ---------------------------------------------------------------------------
__global__ __launch_bounds__(768, 6) void dwproj_kernel(
    const float* __restrict__ x,
    const float* __restrict__ gq, const float* __restrict__ bq,
    const float* __restrict__ mq, const float* __restrict__ vq,
    const float* __restrict__ gk, const float* __restrict__ bk,
    const float* __restrict__ mk, const float* __restrict__ vk,
    const float* __restrict__ gv, const float* __restrict__ bv,
    const float* __restrict__ mv, const float* __restrict__ vv,
    const float* __restrict__ dwT,
    const unsigned short* __restrict__ Wq, const unsigned short* __restrict__ Wk,
    const unsigned short* __restrict__ Wv,
    const float* __restrict__ pqb, const float* __restrict__ pkb,
    const float* __restrict__ pvb,
    unsigned short* __restrict__ Qb, unsigned short* __restrict__ Kb,
    unsigned short* __restrict__ Vb)
{
    __shared__ unsigned short Xs[3][16][200];

    const int b  = blockIdx.x & 7;            // XCD-aware: bid%8 -> XCD
    const int n0 = (blockIdx.x >> 3) * 16;
    const int t = threadIdx.x;
    const int w = t >> 6, l = t & 63, q16 = l & 15, u = l >> 4;

    // ---- W-prefetch: unit 0's fragments, issued before Phase A
    bf16x8 wp0, wp1, wp2, wp3, wp4, wp5;
    {
        const int unit0 = w * 3;
        const int br0 = unit0 / 12;
        const int ob0 = (unit0 % 12) * 16;
        const unsigned short* W0 = (br0 == 0) ? Wq : (br0 == 1) ? Wk : Wv;
        const unsigned short* Wr0 = W0 + (size_t)(ob0 + q16) * kC + u * 8;
        wp0 = *(const bf16x8*)(Wr0 + 0 * 32);
        wp1 = *(const bf16x8*)(Wr0 + 1 * 32);
        wp2 = *(const bf16x8*)(Wr0 + 2 * 32);
        wp3 = *(const bf16x8*)(Wr0 + 3 * 32);
        wp4 = *(const bf16x8*)(Wr0 + 4 * 32);
        wp5 = *(const bf16x8*)(Wr0 + 5 * 32);
    }

    // ---- Phase A: vectorized conv + BN (all 3 branches share x loads)
    {
        const int cg = t % 48;                // 4-channel group
        const int c0 = cg * 4;
        const int pos = t / 48;               // 0..15
        const int n = n0 + pos;
        const int i = n / kW, j = n % kW;

        f32x4 aq = {0.f, 0.f, 0.f, 0.f};
        f32x4 ak = {0.f, 0.f, 0.f, 0.f};
        f32x4 av = {0.f, 0.f, 0.f, 0.f};
        const float* xb = x + (size_t)b * kN * kC + c0;
#pragma unroll
        for (int di = -1; di <= 1; ++di) {
            const int ii = i + di;
            if (ii < 0 || ii >= kH) continue;
#pragma unroll
            for (int dj = -1; dj <= 1; ++dj) {
                const int jj = j + dj;
                if (jj < 0 || jj >= kW) continue;
                const int tap = (di + 1) * 3 + (dj + 1);
                const f32x4 xv = *(const f32x4*)&xb[(size_t)(ii * kW + jj) * kC];
                const f32x4 wq4 = *(const f32x4*)&dwT[(0 * 9 + tap) * kC + c0];
                const f32x4 wk4 = *(const f32x4*)&dwT[(1 * 9 + tap) * kC + c0];
                const f32x4 wv4 = *(const f32x4*)&dwT[(2 * 9 + tap) * kC + c0];
                aq += xv * wq4;
                ak += xv * wk4;
                av += xv * wv4;
            }
        }
        const f32x4 g0 = *(const f32x4*)&gq[c0], b0 = *(const f32x4*)&bq[c0];
        const f32x4 m0 = *(const f32x4*)&mq[c0], v0 = *(const f32x4*)&vq[c0];
        const f32x4 g1 = *(const f32x4*)&gk[c0], b1 = *(const f32x4*)&bk[c0];
        const f32x4 m1 = *(const f32x4*)&mk[c0], v1 = *(const f32x4*)&vk[c0];
        const f32x4 g2 = *(const f32x4*)&gv[c0], b2 = *(const f32x4*)&bv[c0];
        const f32x4 m2 = *(const f32x4*)&mv[c0], v2 = *(const f32x4*)&vv[c0];
        ushort4 pq, pk, pv;
        unsigned short* qq = &pq.x;
        unsigned short* qk = &pk.x;
        unsigned short* qv = &pv.x;
#pragma unroll
        for (int e = 0; e < 4; ++e) {
            const float iq = g0[e] * rsqrtf(v0[e] + kEPS);
            const float ik = g1[e] * rsqrtf(v1[e] + kEPS);
            const float iv = g2[e] * rsqrtf(v2[e] + kEPS);
            qq[e] = f2bf(aq[e] * iq + (b0[e] - m0[e] * iq));
            qk[e] = f2bf(ak[e] * ik + (b1[e] - m1[e] * ik));
            qv[e] = f2bf(av[e] * iv + (b2[e] - m2[e] * iv));
        }
        *(ushort4*)&Xs[0][pos][c0] = pq;
        *(ushort4*)&Xs[1][pos][c0] = pk;
        *(ushort4*)&Xs[2][pos][c0] = pv;
    }
    __syncthreads();

    // ---- Phase B: projection MFMA, 3 units per wave (unit 0 from prefetch)
#pragma unroll
    for (int k3 = 0; k3 < 3; ++k3) {
        const int unit = w * 3 + k3;                  // 0..35
        const int br = unit / 12;
        const int ob = (unit % 12) * 16;
        const unsigned short* W = (br == 0) ? Wq : (br == 1) ? Wk : Wv;
        const float* bias       = (br == 0) ? pqb : (br == 1) ? pkb : pvb;

        f32x4 acc = {0.f, 0.f, 0.f, 0.f};
        const unsigned short* Wr = W + (size_t)(ob + q16) * kC + u * 8;
#pragma unroll
        for (int kk = 0; kk < 6; ++kk) {
            const bf16x8 wa = (k3 == 0)
                ? (kk == 0 ? wp0 : kk == 1 ? wp1 : kk == 2 ? wp2
                   : kk == 3 ? wp3 : kk == 4 ? wp4 : wp5)
                : *(const bf16x8*)(Wr + kk * 32);
            const bf16x8 xa = *(const bf16x8*)&Xs[br][q16][u * 8 + kk * 32];
            acc = __builtin_amdgcn_mfma_f32_16x16x32_bf16(wa, xa, acc, 0, 0, 0);
        }
        const int hh = ob >> 5;
        const int ch0 = (ob & 31) + 4 * u;
        const f32x4 bi = *(const f32x4*)&bias[ob + 4 * u];
        const int n = n0 + q16;
        if (br < 2) {
            const float sc = (br == 0) ? kQS : 1.0f;
            ushort4 p;
            p.x = f2bf((acc[0] + bi[0]) * sc);
            p.y = f2bf((acc[1] + bi[1]) * sc);
            p.z = f2bf((acc[2] + bi[2]) * sc);
            p.w = f2bf((acc[3] + bi[3]) * sc);
            unsigned short* dst = ((br == 0) ? Qb : Kb) +
                ((size_t)(b * kHEADS + hh) * kNP + n) * 32 + ch0;
            *(ushort4*)dst = p;
        } else {
            unsigned short* dst = Vb +
                ((size_t)(b * kHEADS + hh) * 32 + ch0) * kNP + n;
            dst[0 * kNP] = f2bf(acc[0] + bi[0]);
            dst[1 * kNP] = f2bf(acc[1] + bi[1]);
            dst[2 * kNP] = f2bf(acc[2] + bi[2]);
            dst[3 * kNP] = f2bf(acc[3] + bi[3]);
        }
    }
}

// ---------------------------------------------------------------------------
// K2: FUSED attention + output projection, 32-QUERY BLOCKS (no key-split).
// Block = (b, 32-query tile): grid 200 (8 b x 25 qt), 768 threads.
// Wave (h = w%6, qs = w/6): head h, query sub-tile qs -> i0 = qt*32+qs*16;
// each wave runs the FULL 25-tile K-loop (fixed-shift softmax, K-prefetch,
// setprio). Halves K/V L2 re-reads per batch (49 -> 25 blocks).
// Tail (qt=24,qs=1): i0=784 invalid -> compute discarded, stores guarded.
// AO -> LDS AOs[2][16][200] bf16; one barrier; outproj 24 units (2/wave),
// g=4 broadcast stores guarded at n<784. XCD-aware b = bid & 7.
// ---------------------------------------------------------------------------
__global__ __launch_bounds__(768, 6) void attnout_kernel(
    const unsigned short* __restrict__ Qbf, const unsigned short* __restrict__ Kbf,
    const unsigned short* __restrict__ Vbf, const unsigned short* __restrict__ Wo,
    const float* __restrict__ pob, float* __restrict__ Y)
{
    __shared__ unsigned short AOs[2][16][200];

    const int b    = blockIdx.x & 7;          // XCD-aware: bid%8 -> XCD
    const int base = (blockIdx.x >> 3) * 32;  // query-tile base (0..768)
    const int t = threadIdx.x;
    const int w = t >> 6;
    const int h  = w % 6;            // head
    const int qs = w / 6;            // query sub-tile 0/1
    const int i0 = base + qs * 16;
    const bool valid = (i0 < kN);
    const int l = t & 63;
    const int q16 = l & 15;
    const int u = l >> 4;

    const unsigned short* Qp = Qbf + ((size_t)(b * kHEADS + h) * kNP + i0) * 32;
    const unsigned short* Kp = Kbf + (size_t)(b * kHEADS + h) * kNP * 32;
    const unsigned short* Vr0 = Vbf + ((size_t)(b * kHEADS + h) * 32 + q16) * kNP;
    const unsigned short* Vr1 = Vr0 + (size_t)16 * kNP;

    const bf16x8 qa = *(const bf16x8*)(Qp + q16 * 32 + u * 8);

    f32x4 oa0 = {0.f, 0.f, 0.f, 0.f};
    f32x4 oa1 = {0.f, 0.f, 0.f, 0.f};
    f32x4 la  = {0.f, 0.f, 0.f, 0.f};
    f32x4 lb  = {0.f, 0.f, 0.f, 0.f};

    bf16x8 kc0 = *(const bf16x8*)(Kp + (size_t)(0 + q16) * 32 + u * 8);
    bf16x8 kc1 = *(const bf16x8*)(Kp + (size_t)(16 + q16) * 32 + u * 8);
    bf16x8 kn0, kn1;

    for (int tile = 0; tile < 24; ++tile) {
        const int t0 = tile * 32;
        if (tile + 1 < 24) {
            const int t1 = t0 + 32;
            kn0 = *(const bf16x8*)(Kp + (size_t)(t1 + q16) * 32 + u * 8);
            kn1 = *(const bf16x8*)(Kp + (size_t)(t1 + 16 + q16) * 32 + u * 8);
        }
        VU v0, v1;
        v0.hlf[0] = *(const ushort4*)(Vr0 + t0 + 4 * u);
        v0.hlf[1] = *(const ushort4*)(Vr0 + t0 + 16 + 4 * u);
        v1.hlf[0] = *(const ushort4*)(Vr1 + t0 + 4 * u);
        v1.hlf[1] = *(const ushort4*)(Vr1 + t0 + 16 + 4 * u);
        __builtin_amdgcn_s_setprio(1);
        f32x4 d0 = {0.f, 0.f, 0.f, 0.f};
        f32x4 d1 = {0.f, 0.f, 0.f, 0.f};
        d0 = __builtin_amdgcn_mfma_f32_16x16x32_bf16(kc0, qa, d0, 0, 0, 0);
        d1 = __builtin_amdgcn_mfma_f32_16x16x32_bf16(kc1, qa, d1, 0, 0, 0);
        f32x4 ve0, ve1;
        ve0[0] = fexp2(d0[0]); ve0[1] = fexp2(d0[1]);
        ve0[2] = fexp2(d0[2]); ve0[3] = fexp2(d0[3]);
        ve1[0] = fexp2(d1[0]); ve1[1] = fexp2(d1[1]);
        ve1[2] = fexp2(d1[2]); ve1[3] = fexp2(d1[3]);
        la += ve0; lb += ve1;
        union { unsigned int wd[4]; bf16x8 v; } pa;
        asm("v_cvt_pk_bf16_f32 %0, %1, %2" : "=v"(pa.wd[0]) : "v"(ve0[0]), "v"(ve0[1]));
        asm("v_cvt_pk_bf16_f32 %0, %1, %2" : "=v"(pa.wd[1]) : "v"(ve0[2]), "v"(ve0[3]));
        asm("v_cvt_pk_bf16_f32 %0, %1, %2" : "=v"(pa.wd[2]) : "v"(ve1[0]), "v"(ve1[1]));
        asm("v_cvt_pk_bf16_f32 %0, %1, %2" : "=v"(pa.wd[3]) : "v"(ve1[2]), "v"(ve1[3]));
        oa0 = __builtin_amdgcn_mfma_f32_16x16x32_bf16(pa.v, v0.v, oa0, 0, 0, 0);
        oa1 = __builtin_amdgcn_mfma_f32_16x16x32_bf16(pa.v, v1.v, oa1, 0, 0, 0);
        __builtin_amdgcn_s_setprio(0);
        kc0 = kn0; kc1 = kn1;
    }
    { // ---- tile 24 peeled: keys 768..783 valid; V pads = reg zeros
        const int t0 = 768;
        const bf16x8 ka0 = *(const bf16x8*)(Kp + (size_t)(t0 + q16) * 32 + u * 8);
        VU v0, v1;
        const ushort4 z4 = {0, 0, 0, 0};
        v0.hlf[0] = *(const ushort4*)(Vr0 + t0 + 4 * u);
        v0.hlf[1] = z4;
        v1.hlf[0] = *(const ushort4*)(Vr1 + t0 + 4 * u);
        v1.hlf[1] = z4;
        f32x4 d0 = {0.f, 0.f, 0.f, 0.f};
        d0 = __builtin_amdgcn_mfma_f32_16x16x32_bf16(ka0, qa, d0, 0, 0, 0);
        f32x4 ve0;
        ve0[0] = fexp2(d0[0]); ve0[1] = fexp2(d0[1]);
        ve0[2] = fexp2(d0[2]); ve0[3] = fexp2(d0[3]);
        la += ve0;
        union { unsigned int wd[4]; bf16x8 v; } pa;
        asm("v_cvt_pk_bf16_f32 %0, %1, %2" : "=v"(pa.wd[0]) : "v"(ve0[0]), "v"(ve0[1]));
        asm("v_cvt_pk_bf16_f32 %0, %1, %2" : "=v"(pa.wd[1]) : "v"(ve0[2]), "v"(ve0[3]));
        pa.wd[2] = 0u;
        pa.wd[3] = 0u;
        oa0 = __builtin_amdgcn_mfma_f32_16x16x32_bf16(pa.v, v0.v, oa0, 0, 0, 0);
        oa1 = __builtin_amdgcn_mfma_f32_16x16x32_bf16(pa.v, v1.v, oa1, 0, 0, 0);
    }
    float lsum = ((la[0] + la[1]) + (la[2] + la[3])) +
                 ((lb[0] + lb[1]) + (lb[2] + lb[3]));
    lsum += __shfl_xor(lsum, 16);
    lsum += __shfl_xor(lsum, 32);
    const float rinv = 1.0f / lsum;
    const float r0 = __shfl(rinv, u * 4 + 0);
    const float r1 = __shfl(rinv, u * 4 + 1);
    const float r2 = __shfl(rinv, u * 4 + 2);
    const float r3 = __shfl(rinv, u * 4 + 3);
    if (valid) {
        AOs[qs][4 * u + 0][h * 32 + q16] = f2bf(oa0[0] * r0);
        AOs[qs][4 * u + 1][h * 32 + q16] = f2bf(oa0[1] * r1);
        AOs[qs][4 * u + 2][h * 32 + q16] = f2bf(oa0[2] * r2);
        AOs[qs][4 * u + 3][h * 32 + q16] = f2bf(oa0[3] * r3);
        AOs[qs][4 * u + 0][h * 32 + 16 + q16] = f2bf(oa1[0] * r0);
        AOs[qs][4 * u + 1][h * 32 + 16 + q16] = f2bf(oa1[1] * r1);
        AOs[qs][4 * u + 2][h * 32 + 16 + q16] = f2bf(oa1[2] * r2);
        AOs[qs][4 * u + 3][h * 32 + 16 + q16] = f2bf(oa1[3] * r3);
    }
    __syncthreads();

    // ---- output projection: 2 units per wave (12 o-tiles x 2 q-subtiles)
#pragma unroll
    for (int k2 = 0; k2 < 2; ++k2) {
        const int unit = w * 2 + k2;                  // 0..23
        const int qsel = unit / 12;
        const int ob = (unit % 12) * 16;
        f32x4 acc = {0.f, 0.f, 0.f, 0.f};
        const unsigned short* Wr = Wo + (size_t)(ob + q16) * kC + u * 8;
#pragma unroll
        for (int kk = 0; kk < 6; ++kk) {
            const bf16x8 wa = *(const bf16x8*)(Wr + kk * 32);
            const bf16x8 xa = *(const bf16x8*)&AOs[qsel][q16][u * 8 + kk * 32];
            acc = __builtin_amdgcn_mfma_f32_16x16x32_bf16(wa, xa, acc, 0, 0, 0);
        }
        const int n = base + qsel * 16 + q16;
        if (n < kN) {
            const f32x4 bi = *(const f32x4*)&pob[ob + 4 * u];
#pragma unroll
            for (int r = 0; r < 4; ++r) {
                const int o = ob + 4 * u + r;
                const float val = acc[r] + bi[r];
                float* yp = Y + (((size_t)b * kC + o) * kG) * kN + n;
                yp[0 * kN] = val;
                yp[1 * kN] = val;
                yp[2 * kN] = val;
                yp[3 * kN] = val;
            }
        }
    }
}

extern "C" void kernel_launch(void* const* d_in, const int* in_sizes, int n_in,
                              void* d_out, int out_size, void* d_ws, size_t ws_size,
                              hipStream_t stream) {
    const float* x     = (const float*)d_in[0];
    // d_in[1]=h, d_in[2]=w (always 28; ignored)
    const float* dwq_w = (const float*)d_in[3];
    const float* bnq_g = (const float*)d_in[4];
    const float* bnq_b = (const float*)d_in[5];
    const float* bnq_m = (const float*)d_in[6];
    const float* bnq_v = (const float*)d_in[7];
    const float* pq_w  = (const float*)d_in[8];
    const float* pq_b  = (const float*)d_in[9];
    const float* dwk_w = (const float*)d_in[10];
    const float* bnk_g = (const float*)d_in[11];
    const float* bnk_b = (const float*)d_in[12];
    const float* bnk_m = (const float*)d_in[13];
    const float* bnk_v = (const float*)d_in[14];
    const float* pk_w  = (const float*)d_in[15];
    const float* pk_b  = (const float*)d_in[16];
    const float* dwv_w = (const float*)d_in[17];
    const float* bnv_g = (const float*)d_in[18];
    const float* bnv_b = (const float*)d_in[19];
    const float* bnv_m = (const float*)d_in[20];
    const float* bnv_v = (const float*)d_in[21];
    const float* pv_w  = (const float*)d_in[22];
    const float* pv_b  = (const float*)d_in[23];
    const float* po_w  = (const float*)d_in[24];
    const float* po_b  = (const float*)d_in[25];

    unsigned short* ws = (unsigned short*)d_ws;
    const size_t QSZ = (size_t)kB * kHEADS * kNP * 32;  // 1,228,800
    unsigned short* Qb = ws;
    unsigned short* Kb = Qb + QSZ;
    unsigned short* Vb = Kb + QSZ;
    unsigned short* Wq = Vb + QSZ;
    unsigned short* Wk = Wq + kC * kC;
    unsigned short* Wv = Wk + kC * kC;
    unsigned short* Wo = Wv + kC * kC;
    float* dwT = (float*)(Wo + kC * kC);     // 5184 f32; offset is 4B-aligned

    prep_kernel<<<dim3(165), dim3(256), 0, stream>>>(
        pq_w, pk_w, pv_w, po_w, dwq_w, dwk_w, dwv_w,
        Wq, Wk, Wv, Wo, dwT);

    dwproj_kernel<<<dim3(kB * 49), dim3(768), 0, stream>>>(
        x,
        bnq_g, bnq_b, bnq_m, bnq_v,
        bnk_g, bnk_b, bnk_m, bnk_v,
        bnv_g, bnv_b, bnv_m, bnv_v,
        dwT, Wq, Wk, Wv, pq_b, pk_b, pv_b, Qb, Kb, Vb);

    attnout_kernel<<<dim3(kB * 25), dim3(768), 0, stream>>>(
        Qb, Kb, Vb, Wo, po_b, (float*)d_out);
}

// Round 21
// 66.357 us; speedup vs baseline: 1.0179x; 1.0179x over previous
//
#include <hip/hip_runtime.h>
#include <math.h>

// Problem constants (ConvAttention: B=8, C=192, H=W=28, heads=6, ch=32, G=4)
namespace {
constexpr int kB = 8;
constexpr int kC = 192;
constexpr int kH = 28;
constexpr int kW = 28;
constexpr int kN = 784;          // kH * kW
constexpr int kHEADS = 6;
constexpr int kG = 4;
constexpr float kEPS = 1e-5f;
// 192^-0.5 * log2(e): scores in log2-units so softmax uses native 2^x.
// FIXED shift m=0 (shift-invariant; scores are O(0.3) in log2 units).
constexpr float kQS = 0.07216878364870322f * 1.4426950408889634f;
constexpr int kNP = 800;         // padded key-row stride (25 tiles of 32)
}

typedef __attribute__((ext_vector_type(8))) short bf16x8;
typedef __attribute__((ext_vector_type(4))) float f32x4;

union VU { ushort4 hlf[2]; bf16x8 v; };

// f32 -> bf16 bits, round-to-nearest-even
static __device__ __forceinline__ unsigned short f2bf(float f) {
    union { float f; unsigned int u; } v; v.f = f;
    unsigned int r = v.u + 0x7fffu + ((v.u >> 16) & 1u);
    return (unsigned short)(r >> 16);
}

static __device__ __forceinline__ float fexp2(float x) {
    return __builtin_amdgcn_exp2f(x);   // native v_exp_f32 (2^x)
}

// ---------------------------------------------------------------------------
// K0: prep. Wq/Wk/Wv f32->bf16; Wo bf16 with column perm
// Wo'[o][h*32+c] = po_w[o][c*6+h]; dwT[br][tap][c] = dw_br[c*9+tap] (f32,
// tap-major so dwproj loads 4-channel groups as f32x4).
// 165 blocks x 256 threads = 42240 >= 36864 (W) + 5184 (dwT).
// ---------------------------------------------------------------------------
__global__ __launch_bounds__(256) void prep_kernel(
    const float* __restrict__ pqw, const float* __restrict__ pkw,
    const float* __restrict__ pvw, const float* __restrict__ pow_,
    const float* __restrict__ dwq, const float* __restrict__ dwk,
    const float* __restrict__ dwv,
    unsigned short* __restrict__ Wq, unsigned short* __restrict__ Wk,
    unsigned short* __restrict__ Wv, unsigned short* __restrict__ Wo,
    float* __restrict__ dwT)
{
    const int aux = blockIdx.x * 256 + threadIdx.x;
    if (aux < 36864) {
        const int e0 = aux * 4;
        const int mat = e0 / (kC * kC);
        const int r = e0 % (kC * kC);
        if (mat < 3) {
            const float* src = (mat == 0) ? pqw : (mat == 1) ? pkw : pvw;
            unsigned short* dst = (mat == 0) ? Wq : (mat == 1) ? Wk : Wv;
            const f32x4 v = *(const f32x4*)&src[r];
            ushort4 p;
            p.x = f2bf(v[0]); p.y = f2bf(v[1]); p.z = f2bf(v[2]); p.w = f2bf(v[3]);
            *(ushort4*)&dst[r] = p;
        } else {
            const int o = r / kC, c0 = r % kC;
            ushort4 p;
            unsigned short* pp = &p.x;
#pragma unroll
            for (int e = 0; e < 4; ++e) {
                const int c = c0 + e;
                pp[e] = f2bf(pow_[o * kC + (c & 31) * kHEADS + (c >> 5)]);
            }
            *(ushort4*)&Wo[o * kC + c0] = p;
        }
    } else {
        const int r = aux - 36864;           // 0..5375; valid < 5184
        if (r < 3 * 9 * kC) {
            const int br = r / (9 * kC);
            const int rem = r % (9 * kC);
            const int tap = rem / kC, c = rem % kC;
            const float* dw = (br == 0) ? dwq : (br == 1) ? dwk : dwv;
            dwT[r] = dw[c * 9 + tap];
        }
    }
}

// ---------------------------------------------------------------------------
// K1: FUSED dw3x3+BN + 1x1 projection — vectorized Phase A + W-prefetch +
// XCD-AWARE BLOCK MAPPING: b = bid & 7 (dispatch round-robins bid -> XCD,
// so XCD k gets all 49 tiles of batch k; its L2 holds only batch k's data).
// 392 blocks x 768 threads (12 waves).
// ---------------------------------------------------------------------------
__global__ __launch_bounds__(768, 6) void dwproj_kernel(
    const float* __restrict__ x,
    const float* __restrict__ gq, const float* __restrict__ bq,
    const float* __restrict__ mq, const float* __restrict__ vq,
    const float* __restrict__ gk, const float* __restrict__ bk,
    const float* __restrict__ mk, const float* __restrict__ vk,
    const float* __restrict__ gv, const float* __restrict__ bv,
    const float* __restrict__ mv, const float* __restrict__ vv,
    const float* __restrict__ dwT,
    const unsigned short* __restrict__ Wq, const unsigned short* __restrict__ Wk,
    const unsigned short* __restrict__ Wv,
    const float* __restrict__ pqb, const float* __restrict__ pkb,
    const float* __restrict__ pvb,
    unsigned short* __restrict__ Qb, unsigned short* __restrict__ Kb,
    unsigned short* __restrict__ Vb)
{
    __shared__ unsigned short Xs[3][16][200];

    const int b  = blockIdx.x & 7;            // XCD-aware: bid%8 -> XCD
    const int n0 = (blockIdx.x >> 3) * 16;
    const int t = threadIdx.x;
    const int w = t >> 6, l = t & 63, q16 = l & 15, u = l >> 4;

    // ---- W-prefetch: unit 0's fragments, issued before Phase A
    bf16x8 wp0, wp1, wp2, wp3, wp4, wp5;
    {
        const int unit0 = w * 3;
        const int br0 = unit0 / 12;
        const int ob0 = (unit0 % 12) * 16;
        const unsigned short* W0 = (br0 == 0) ? Wq : (br0 == 1) ? Wk : Wv;
        const unsigned short* Wr0 = W0 + (size_t)(ob0 + q16) * kC + u * 8;
        wp0 = *(const bf16x8*)(Wr0 + 0 * 32);
        wp1 = *(const bf16x8*)(Wr0 + 1 * 32);
        wp2 = *(const bf16x8*)(Wr0 + 2 * 32);
        wp3 = *(const bf16x8*)(Wr0 + 3 * 32);
        wp4 = *(const bf16x8*)(Wr0 + 4 * 32);
        wp5 = *(const bf16x8*)(Wr0 + 5 * 32);
    }

    // ---- Phase A: vectorized conv + BN (all 3 branches share x loads)
    {
        const int cg = t % 48;                // 4-channel group
        const int c0 = cg * 4;
        const int pos = t / 48;               // 0..15
        const int n = n0 + pos;
        const int i = n / kW, j = n % kW;

        f32x4 aq = {0.f, 0.f, 0.f, 0.f};
        f32x4 ak = {0.f, 0.f, 0.f, 0.f};
        f32x4 av = {0.f, 0.f, 0.f, 0.f};
        const float* xb = x + (size_t)b * kN * kC + c0;
#pragma unroll
        for (int di = -1; di <= 1; ++di) {
            const int ii = i + di;
            if (ii < 0 || ii >= kH) continue;
#pragma unroll
            for (int dj = -1; dj <= 1; ++dj) {
                const int jj = j + dj;
                if (jj < 0 || jj >= kW) continue;
                const int tap = (di + 1) * 3 + (dj + 1);
                const f32x4 xv = *(const f32x4*)&xb[(size_t)(ii * kW + jj) * kC];
                const f32x4 wq4 = *(const f32x4*)&dwT[(0 * 9 + tap) * kC + c0];
                const f32x4 wk4 = *(const f32x4*)&dwT[(1 * 9 + tap) * kC + c0];
                const f32x4 wv4 = *(const f32x4*)&dwT[(2 * 9 + tap) * kC + c0];
                aq += xv * wq4;
                ak += xv * wk4;
                av += xv * wv4;
            }
        }
        const f32x4 g0 = *(const f32x4*)&gq[c0], b0 = *(const f32x4*)&bq[c0];
        const f32x4 m0 = *(const f32x4*)&mq[c0], v0 = *(const f32x4*)&vq[c0];
        const f32x4 g1 = *(const f32x4*)&gk[c0], b1 = *(const f32x4*)&bk[c0];
        const f32x4 m1 = *(const f32x4*)&mk[c0], v1 = *(const f32x4*)&vk[c0];
        const f32x4 g2 = *(const f32x4*)&gv[c0], b2 = *(const f32x4*)&bv[c0];
        const f32x4 m2 = *(const f32x4*)&mv[c0], v2 = *(const f32x4*)&vv[c0];
        ushort4 pq, pk, pv;
        unsigned short* qq = &pq.x;
        unsigned short* qk = &pk.x;
        unsigned short* qv = &pv.x;
#pragma unroll
        for (int e = 0; e < 4; ++e) {
            const float iq = g0[e] * rsqrtf(v0[e] + kEPS);
            const float ik = g1[e] * rsqrtf(v1[e] + kEPS);
            const float iv = g2[e] * rsqrtf(v2[e] + kEPS);
            qq[e] = f2bf(aq[e] * iq + (b0[e] - m0[e] * iq));
            qk[e] = f2bf(ak[e] * ik + (b1[e] - m1[e] * ik));
            qv[e] = f2bf(av[e] * iv + (b2[e] - m2[e] * iv));
        }
        *(ushort4*)&Xs[0][pos][c0] = pq;
        *(ushort4*)&Xs[1][pos][c0] = pk;
        *(ushort4*)&Xs[2][pos][c0] = pv;
    }
    __syncthreads();

    // ---- Phase B: projection MFMA, 3 units per wave (unit 0 from prefetch)
#pragma unroll
    for (int k3 = 0; k3 < 3; ++k3) {
        const int unit = w * 3 + k3;                  // 0..35
        const int br = unit / 12;
        const int ob = (unit % 12) * 16;
        const unsigned short* W = (br == 0) ? Wq : (br == 1) ? Wk : Wv;
        const float* bias       = (br == 0) ? pqb : (br == 1) ? pkb : pvb;

        f32x4 acc = {0.f, 0.f, 0.f, 0.f};
        const unsigned short* Wr = W + (size_t)(ob + q16) * kC + u * 8;
#pragma unroll
        for (int kk = 0; kk < 6; ++kk) {
            const bf16x8 wa = (k3 == 0)
                ? (kk == 0 ? wp0 : kk == 1 ? wp1 : kk == 2 ? wp2
                   : kk == 3 ? wp3 : kk == 4 ? wp4 : wp5)
                : *(const bf16x8*)(Wr + kk * 32);
            const bf16x8 xa = *(const bf16x8*)&Xs[br][q16][u * 8 + kk * 32];
            acc = __builtin_amdgcn_mfma_f32_16x16x32_bf16(wa, xa, acc, 0, 0, 0);
        }
        const int hh = ob >> 5;
        const int ch0 = (ob & 31) + 4 * u;
        const f32x4 bi = *(const f32x4*)&bias[ob + 4 * u];
        const int n = n0 + q16;
        if (br < 2) {
            const float sc = (br == 0) ? kQS : 1.0f;
            ushort4 p;
            p.x = f2bf((acc[0] + bi[0]) * sc);
            p.y = f2bf((acc[1] + bi[1]) * sc);
            p.z = f2bf((acc[2] + bi[2]) * sc);
            p.w = f2bf((acc[3] + bi[3]) * sc);
            unsigned short* dst = ((br == 0) ? Qb : Kb) +
                ((size_t)(b * kHEADS + hh) * kNP + n) * 32 + ch0;
            *(ushort4*)dst = p;
        } else {
            unsigned short* dst = Vb +
                ((size_t)(b * kHEADS + hh) * 32 + ch0) * kNP + n;
            dst[0 * kNP] = f2bf(acc[0] + bi[0]);
            dst[1 * kNP] = f2bf(acc[1] + bi[1]);
            dst[2 * kNP] = f2bf(acc[2] + bi[2]);
            dst[3 * kNP] = f2bf(acc[3] + bi[3]);
        }
    }
}

// ---------------------------------------------------------------------------
// K2: FUSED attention + output projection, KEY-SPLIT, FIXED-SHIFT softmax,
// K-prefetch + setprio + XCD-AWARE BLOCK MAPPING (b = bid & 7 -> all 49
// query-tiles of batch b land on XCD b; its L2 holds only that batch's
// 600 KB of K/V instead of the full 4.8 MB working set).
// 392 blocks x 768 threads (12 waves).
// ---------------------------------------------------------------------------
__global__ __launch_bounds__(768, 6) void attnout_kernel(
    const unsigned short* __restrict__ Qbf, const unsigned short* __restrict__ Kbf,
    const unsigned short* __restrict__ Vbf, const unsigned short* __restrict__ Wo,
    const float* __restrict__ pob, float* __restrict__ Y)
{
    __shared__ unsigned short AOs[16][200];
    __shared__ float Mrg[6][64][9];

    const int b  = blockIdx.x & 7;            // XCD-aware: bid%8 -> XCD
    const int i0 = (blockIdx.x >> 3) * 16;
    const int t = threadIdx.x;
    const int w = t >> 6;
    const int h = w % 6;             // head
    const int s = w / 6;             // key-half
    const int l = t & 63;
    const int q16 = l & 15;
    const int u = l >> 4;

    const unsigned short* Qp = Qbf + ((size_t)(b * kHEADS + h) * kNP + i0) * 32;
    const unsigned short* Kp = Kbf + (size_t)(b * kHEADS + h) * kNP * 32;
    const unsigned short* Vr0 = Vbf + ((size_t)(b * kHEADS + h) * 32 + q16) * kNP;
    const unsigned short* Vr1 = Vr0 + (size_t)16 * kNP;

    const bf16x8 qa = *(const bf16x8*)(Qp + q16 * 32 + u * 8);

    f32x4 oa0 = {0.f, 0.f, 0.f, 0.f};
    f32x4 oa1 = {0.f, 0.f, 0.f, 0.f};
    f32x4 la  = {0.f, 0.f, 0.f, 0.f};
    f32x4 lb  = {0.f, 0.f, 0.f, 0.f};

    const int tile_begin = s ? 12 : 0;
    const int tile_end   = s ? 24 : 12;

    bf16x8 kc0 = *(const bf16x8*)(Kp + (size_t)(tile_begin * 32 + q16) * 32 + u * 8);
    bf16x8 kc1 = *(const bf16x8*)(Kp + (size_t)(tile_begin * 32 + 16 + q16) * 32 + u * 8);
    bf16x8 kn0, kn1;

    for (int tile = tile_begin; tile < tile_end; ++tile) {
        const int t0 = tile * 32;
        if (tile + 1 < tile_end) {
            const int t1 = t0 + 32;
            kn0 = *(const bf16x8*)(Kp + (size_t)(t1 + q16) * 32 + u * 8);
            kn1 = *(const bf16x8*)(Kp + (size_t)(t1 + 16 + q16) * 32 + u * 8);
        }
        VU v0, v1;
        v0.hlf[0] = *(const ushort4*)(Vr0 + t0 + 4 * u);
        v0.hlf[1] = *(const ushort4*)(Vr0 + t0 + 16 + 4 * u);
        v1.hlf[0] = *(const ushort4*)(Vr1 + t0 + 4 * u);
        v1.hlf[1] = *(const ushort4*)(Vr1 + t0 + 16 + 4 * u);
        __builtin_amdgcn_s_setprio(1);
        f32x4 d0 = {0.f, 0.f, 0.f, 0.f};
        f32x4 d1 = {0.f, 0.f, 0.f, 0.f};
        d0 = __builtin_amdgcn_mfma_f32_16x16x32_bf16(kc0, qa, d0, 0, 0, 0);
        d1 = __builtin_amdgcn_mfma_f32_16x16x32_bf16(kc1, qa, d1, 0, 0, 0);
        f32x4 ve0, ve1;
        ve0[0] = fexp2(d0[0]); ve0[1] = fexp2(d0[1]);
        ve0[2] = fexp2(d0[2]); ve0[3] = fexp2(d0[3]);
        ve1[0] = fexp2(d1[0]); ve1[1] = fexp2(d1[1]);
        ve1[2] = fexp2(d1[2]); ve1[3] = fexp2(d1[3]);
        la += ve0; lb += ve1;
        union { unsigned int wd[4]; bf16x8 v; } pa;
        asm("v_cvt_pk_bf16_f32 %0, %1, %2" : "=v"(pa.wd[0]) : "v"(ve0[0]), "v"(ve0[1]));
        asm("v_cvt_pk_bf16_f32 %0, %1, %2" : "=v"(pa.wd[1]) : "v"(ve0[2]), "v"(ve0[3]));
        asm("v_cvt_pk_bf16_f32 %0, %1, %2" : "=v"(pa.wd[2]) : "v"(ve1[0]), "v"(ve1[1]));
        asm("v_cvt_pk_bf16_f32 %0, %1, %2" : "=v"(pa.wd[3]) : "v"(ve1[2]), "v"(ve1[3]));
        oa0 = __builtin_amdgcn_mfma_f32_16x16x32_bf16(pa.v, v0.v, oa0, 0, 0, 0);
        oa1 = __builtin_amdgcn_mfma_f32_16x16x32_bf16(pa.v, v1.v, oa1, 0, 0, 0);
        __builtin_amdgcn_s_setprio(0);
        kc0 = kn0; kc1 = kn1;
    }
    if (s) { // ---- tile 24 peeled: keys 768..783 valid; V pads = reg zeros
        const int t0 = 768;
        const bf16x8 ka0 = *(const bf16x8*)(Kp + (size_t)(t0 + q16) * 32 + u * 8);
        VU v0, v1;
        const ushort4 z4 = {0, 0, 0, 0};
        v0.hlf[0] = *(const ushort4*)(Vr0 + t0 + 4 * u);
        v0.hlf[1] = z4;
        v1.hlf[0] = *(const ushort4*)(Vr1 + t0 + 4 * u);
        v1.hlf[1] = z4;
        f32x4 d0 = {0.f, 0.f, 0.f, 0.f};
        d0 = __builtin_amdgcn_mfma_f32_16x16x32_bf16(ka0, qa, d0, 0, 0, 0);
        f32x4 ve0;
        ve0[0] = fexp2(d0[0]); ve0[1] = fexp2(d0[1]);
        ve0[2] = fexp2(d0[2]); ve0[3] = fexp2(d0[3]);
        la += ve0;
        union { unsigned int wd[4]; bf16x8 v; } pa;
        asm("v_cvt_pk_bf16_f32 %0, %1, %2" : "=v"(pa.wd[0]) : "v"(ve0[0]), "v"(ve0[1]));
        asm("v_cvt_pk_bf16_f32 %0, %1, %2" : "=v"(pa.wd[1]) : "v"(ve0[2]), "v"(ve0[3]));
        pa.wd[2] = 0u;
        pa.wd[3] = 0u;
        oa0 = __builtin_amdgcn_mfma_f32_16x16x32_bf16(pa.v, v0.v, oa0, 0, 0, 0);
        oa1 = __builtin_amdgcn_mfma_f32_16x16x32_bf16(pa.v, v1.v, oa1, 0, 0, 0);
    }
    float psum = ((la[0] + la[1]) + (la[2] + la[3])) +
                 ((lb[0] + lb[1]) + (lb[2] + lb[3]));

    if (s == 1) {                    // publish partials
        float* Mp = Mrg[h][l];
        Mp[0] = oa0[0]; Mp[1] = oa0[1]; Mp[2] = oa0[2]; Mp[3] = oa0[3];
        Mp[4] = oa1[0]; Mp[5] = oa1[1]; Mp[6] = oa1[2]; Mp[7] = oa1[3];
        Mp[8] = psum;
    }
    __syncthreads();
    if (s == 0) {                    // merge (pure add) + normalize + AO write
        const float* Mp = Mrg[h][l];
        oa0[0] += Mp[0]; oa0[1] += Mp[1]; oa0[2] += Mp[2]; oa0[3] += Mp[3];
        oa1[0] += Mp[4]; oa1[1] += Mp[5]; oa1[2] += Mp[6]; oa1[3] += Mp[7];
        float lsum = psum + Mp[8];
        lsum += __shfl_xor(lsum, 16);
        lsum += __shfl_xor(lsum, 32);
        const float rinv = 1.0f / lsum;
        const float r0 = __shfl(rinv, u * 4 + 0);
        const float r1 = __shfl(rinv, u * 4 + 1);
        const float r2 = __shfl(rinv, u * 4 + 2);
        const float r3 = __shfl(rinv, u * 4 + 3);
        AOs[4 * u + 0][h * 32 + q16] = f2bf(oa0[0] * r0);
        AOs[4 * u + 1][h * 32 + q16] = f2bf(oa0[1] * r1);
        AOs[4 * u + 2][h * 32 + q16] = f2bf(oa0[2] * r2);
        AOs[4 * u + 3][h * 32 + q16] = f2bf(oa0[3] * r3);
        AOs[4 * u + 0][h * 32 + 16 + q16] = f2bf(oa1[0] * r0);
        AOs[4 * u + 1][h * 32 + 16 + q16] = f2bf(oa1[1] * r1);
        AOs[4 * u + 2][h * 32 + 16 + q16] = f2bf(oa1[2] * r2);
        AOs[4 * u + 3][h * 32 + 16 + q16] = f2bf(oa1[3] * r3);
    }
    __syncthreads();

    // ---- output projection: 1 o-tile per wave
    {
        const int ob = w * 16;
        f32x4 acc = {0.f, 0.f, 0.f, 0.f};
        const unsigned short* Wr = Wo + (size_t)(ob + q16) * kC + u * 8;
#pragma unroll
        for (int kk = 0; kk < 6; ++kk) {
            const bf16x8 wa = *(const bf16x8*)(Wr + kk * 32);
            const bf16x8 xa = *(const bf16x8*)&AOs[q16][u * 8 + kk * 32];
            acc = __builtin_amdgcn_mfma_f32_16x16x32_bf16(wa, xa, acc, 0, 0, 0);
        }
        const f32x4 bi = *(const f32x4*)&pob[ob + 4 * u];
        const int n = i0 + q16;
#pragma unroll
        for (int r = 0; r < 4; ++r) {
            const int o = ob + 4 * u + r;
            const float val = acc[r] + bi[r];
            float* yp = Y + (((size_t)b * kC + o) * kG) * kN + n;
            yp[0 * kN] = val;
            yp[1 * kN] = val;
            yp[2 * kN] = val;
            yp[3 * kN] = val;
        }
    }
}

extern "C" void kernel_launch(void* const* d_in, const int* in_sizes, int n_in,
                              void* d_out, int out_size, void* d_ws, size_t ws_size,
                              hipStream_t stream) {
    const float* x     = (const float*)d_in[0];
    // d_in[1]=h, d_in[2]=w (always 28; ignored)
    const float* dwq_w = (const float*)d_in[3];
    const float* bnq_g = (const float*)d_in[4];
    const float* bnq_b = (const float*)d_in[5];
    const float* bnq_m = (const float*)d_in[6];
    const float* bnq_v = (const float*)d_in[7];
    const float* pq_w  = (const float*)d_in[8];
    const float* pq_b  = (const float*)d_in[9];
    const float* dwk_w = (const float*)d_in[10];
    const float* bnk_g = (const float*)d_in[11];
    const float* bnk_b = (const float*)d_in[12];
    const float* bnk_m = (const float*)d_in[13];
    const float* bnk_v = (const float*)d_in[14];
    const float* pk_w  = (const float*)d_in[15];
    const float* pk_b  = (const float*)d_in[16];
    const float* dwv_w = (const float*)d_in[17];
    const float* bnv_g = (const float*)d_in[18];
    const float* bnv_b = (const float*)d_in[19];
    const float* bnv_m = (const float*)d_in[20];
    const float* bnv_v = (const float*)d_in[21];
    const float* pv_w  = (const float*)d_in[22];
    const float* pv_b  = (const float*)d_in[23];
    const float* po_w  = (const float*)d_in[24];
    const float* po_b  = (const float*)d_in[25];

    unsigned short* ws = (unsigned short*)d_ws;
    const size_t QSZ = (size_t)kB * kHEADS * kNP * 32;  // 1,228,800
    unsigned short* Qb = ws;
    unsigned short* Kb = Qb + QSZ;
    unsigned short* Vb = Kb + QSZ;
    unsigned short* Wq = Vb + QSZ;
    unsigned short* Wk = Wq + kC * kC;
    unsigned short* Wv = Wk + kC * kC;
    unsigned short* Wo = Wv + kC * kC;
    float* dwT = (float*)(Wo + kC * kC);     // 5184 f32; offset is 4B-aligned

    prep_kernel<<<dim3(165), dim3(256), 0, stream>>>(
        pq_w, pk_w, pv_w, po_w, dwq_w, dwk_w, dwv_w,
        Wq, Wk, Wv, Wo, dwT);

    dwproj_kernel<<<dim3(kB * 49), dim3(768), 0, stream>>>(
        x,
        bnq_g, bnq_b, bnq_m, bnq_v,
        bnk_g, bnk_b, bnk_m, bnk_v,
        bnv_g, bnv_b, bnv_m, bnv_v,
        dwT, Wq, Wk, Wv, pq_b, pk_b, pv_b, Qb, Kb, Vb);

    attnout_kernel<<<dim3(kB * 49), dim3(768), 0, stream>>>(
        Qb, Kb, Vb, Wo, po_b, (float*)d_out);
}